// Round 5
// baseline (148.716 us; speedup 1.0000x reference)
//
#include <hip/hip_runtime.h>
#include <math.h>

#define BB 8
#define NCC 1024
#define NTT 1024
#define HH 128
#define DYY 32
#define NCG 8                    /* n chunk-groups per batch row */
#define NTG (BB * (NTT / 64))    /* 128 target-groups of 64 */
#define HSTRIDE 129              /* odd stride: bank=(p+k)%32, conflict-free for p-major lanes */

// ---------------- K1: fused MLP  sig = exp(mlp(xt))  ----------------
// 256 blocks x 512 threads; block = 32 points. thread = (jg = tid>>5, p = tid&31):
// a wave holds 2 jg values x 32 points, so the two float4 W-loads per k are
// 64 B unique per wave (L1-line broadcast, ~4-8 clk) instead of 512 B (32 clk
// with the old p-major mapping). h reads: 32 unique LDS words, 2-way broadcast
// (free). No s_loads in the loop, no big per-thread arrays (round-2 lesson).
__global__ __launch_bounds__(512) void k_mlp(const float* __restrict__ xt,
                                             const float* __restrict__ W0,
                                             const float* __restrict__ b0,
                                             const float* __restrict__ W1,
                                             const float* __restrict__ b1,
                                             const float* __restrict__ W2,
                                             const float* __restrict__ b2,
                                             const float* __restrict__ W3,
                                             const float* __restrict__ b3,
                                             float* __restrict__ sig) {
    const int tid = threadIdx.x;
    const int jg = tid >> 5;        // 0..15 col-group; only 2 per wave
    const int p = tid & 31;         // 0..31 point within block
    const int j0 = jg * 8;
    const int row0 = blockIdx.x * 32;

    __shared__ float hbuf[32 * HSTRIDE];      // 16.1 KB
    __shared__ float red[32 * 16 * 3];        // L3 partials, 6 KB

    // ---- L0: o = relu(xt @ W0 + b0) for my (p, 8 cols) ----
    const float* xr = xt + (size_t)(row0 + p) * 3;
    float x0 = xr[0], x1 = xr[1], x2 = xr[2];
    float o[8];
#pragma unroll
    for (int jj = 0; jj < 8; ++jj) {
        int j = j0 + jj;
        float a = b0[j];
        a = fmaf(x0, W0[0 * HH + j], a);
        a = fmaf(x1, W0[1 * HH + j], a);
        a = fmaf(x2, W0[2 * HH + j], a);
        o[jj] = fmaxf(a, 0.f);
    }
#pragma unroll
    for (int jj = 0; jj < 8; ++jj) hbuf[p * HSTRIDE + j0 + jj] = o[jj];
    __syncthreads();

    // ---- L1, L2: o = relu(h @ W + b) ----
    for (int l = 0; l < 2; ++l) {
        const float* __restrict__ W = (l == 0) ? W1 : W2;
        const float* __restrict__ bi = (l == 0) ? b1 : b2;
        const float4* __restrict__ Wv = (const float4*)W;   // [k][32 float4]
        float acc[8];
#pragma unroll
        for (int jj = 0; jj < 8; ++jj) acc[jj] = bi[j0 + jj];
#pragma unroll 16
        for (int k = 0; k < HH; ++k) {
            float hv = hbuf[p * HSTRIDE + k];
            float4 wa = Wv[k * 32 + jg * 2];
            float4 wb = Wv[k * 32 + jg * 2 + 1];
            acc[0] = fmaf(hv, wa.x, acc[0]);
            acc[1] = fmaf(hv, wa.y, acc[1]);
            acc[2] = fmaf(hv, wa.z, acc[2]);
            acc[3] = fmaf(hv, wa.w, acc[3]);
            acc[4] = fmaf(hv, wb.x, acc[4]);
            acc[5] = fmaf(hv, wb.y, acc[5]);
            acc[6] = fmaf(hv, wb.z, acc[6]);
            acc[7] = fmaf(hv, wb.w, acc[7]);
        }
        __syncthreads();        // all reads of hbuf complete
#pragma unroll
        for (int jj = 0; jj < 8; ++jj) o[jj] = fmaxf(acc[jj], 0.f);
        if (l == 0) {
#pragma unroll
            for (int jj = 0; jj < 8; ++jj) hbuf[p * HSTRIDE + j0 + jj] = o[jj];
            __syncthreads();
        }
    }

    // ---- L3 + exp: partial over my 8 cols, reduce across the 16 jg threads ----
    float p0 = 0.f, p1 = 0.f, p2 = 0.f;
#pragma unroll
    for (int jj = 0; jj < 8; ++jj) {
        int j = j0 + jj;
        p0 = fmaf(o[jj], W3[j * 3 + 0], p0);
        p1 = fmaf(o[jj], W3[j * 3 + 1], p1);
        p2 = fmaf(o[jj], W3[j * 3 + 2], p2);
    }
    red[(p * 16 + jg) * 3 + 0] = p0;
    red[(p * 16 + jg) * 3 + 1] = p1;
    red[(p * 16 + jg) * 3 + 2] = p2;
    __syncthreads();
    if (tid < 96) {
        int r = tid / 3, c = tid - r * 3;
        float v = b3[c];
#pragma unroll
        for (int g = 0; g < 16; ++g) v += red[(r * 16 + g) * 3 + c];
        sig[(size_t)(row0 + r) * 3 + c] = __expf(v);
    }
}

// ---------------- K2: attention partials ----------------
// Block = (tg, cg): 4 waves, each wave a 32-n subchunk; lane = one target.
// P<=0 always (sig>0, squares>=0): exp(P)<=1, no max subtraction, partials sum.
// xc/yc addresses are wave-uniform -> scalar K$ loads; acc FMAs take yc as SGPR.
__global__ __launch_bounds__(256) void k_attn(const float* __restrict__ xc,
                                              const float* __restrict__ yc,
                                              const float* __restrict__ xt,
                                              const float* __restrict__ sig,
                                              float* __restrict__ pO,
                                              float* __restrict__ pl) {
    const int tid = threadIdx.x;
    const int w = tid >> 6, lane = tid & 63;
    const int tg = blockIdx.x;      // 0..127
    const int cg = blockIdx.y;      // 0..7
    const int b = tg >> 4;
    const size_t bt = (size_t)tg * 64 + lane;

    float s0 = sig[bt * 3 + 0], s1 = sig[bt * 3 + 1], s2 = sig[bt * 3 + 2];
    float a0 = xt[bt * 3 + 0], a1 = xt[bt * 3 + 1], a2 = xt[bt * 3 + 2];

    float acc[DYY];
#pragma unroll
    for (int d = 0; d < DYY; ++d) acc[d] = 0.f;
    float l = 0.f;

    const int n0 = cg * 128 + w * 32;
    const float* __restrict__ xcb = xc + ((size_t)b * NCC + n0) * 3;
    const float* __restrict__ ycb = yc + ((size_t)b * NCC + n0) * DYY;
#pragma unroll 4
    for (int nn = 0; nn < 32; ++nn) {
        float d0 = xcb[nn * 3 + 0] - a0;
        float d1 = xcb[nn * 3 + 1] - a1;
        float d2 = xcb[nn * 3 + 2] - a2;
        float p = fmaf(s0, d0 * d0, fmaf(s1, d1 * d1, s2 * (d2 * d2)));
        float e = __expf(-p);
        l += e;
#pragma unroll
        for (int d = 0; d < DYY; ++d) acc[d] = fmaf(e, ycb[nn * DYY + d], acc[d]);
    }

    __shared__ float ps[4 * 2048];   // [w][d*64+lane] — lanes consecutive, conflict-free
    __shared__ float pls[4 * 64];
#pragma unroll
    for (int d = 0; d < DYY; ++d) ps[w * 2048 + d * 64 + lane] = acc[d];
    pls[w * 64 + lane] = l;
    __syncthreads();

    const size_t base = ((size_t)tg * NCG + cg) * 2048;
    for (int i = tid; i < 2048; i += 256)
        pO[base + i] = ps[i] + ps[2048 + i] + ps[4096 + i] + ps[6144 + i];
    if (tid < 64)
        pl[((size_t)tg * NCG + cg) * 64 + tid] =
            pls[tid] + pls[64 + tid] + pls[128 + tid] + pls[192 + tid];
}

// ---------------- K3: combine chunk-group partials, normalize, write out ----------------
__global__ __launch_bounds__(256) void k_combine(const float* __restrict__ pO,
                                                 const float* __restrict__ pl,
                                                 float* __restrict__ out) {
    const int tg = blockIdx.x;      // 0..127
    const int tid = threadIdx.x;
    __shared__ float sm[32 * 65];   // [d][tl], stride 65 kills transpose conflicts
    __shared__ float sl[64];
    for (int i = tid; i < 2048; i += 256) {
        float s = 0.f;
#pragma unroll
        for (int c = 0; c < NCG; ++c) s += pO[((size_t)tg * NCG + c) * 2048 + i];
        sm[(i >> 6) * 65 + (i & 63)] = s;   // i = d*64+tl
    }
    if (tid < 64) {
        float lsum = 0.f;
#pragma unroll
        for (int c = 0; c < NCG; ++c) lsum += pl[((size_t)tg * NCG + c) * 64 + tid];
        sl[tid] = lsum;
    }
    __syncthreads();
    for (int i = tid; i < 2048; i += 256) {
        int tl = i >> 5, d = i & 31;
        out[(size_t)tg * 2048 + i] = sm[d * 65 + tl] / sl[tl];
    }
}

extern "C" void kernel_launch(void* const* d_in, const int* in_sizes, int n_in,
                              void* d_out, int out_size, void* d_ws, size_t ws_size,
                              hipStream_t stream) {
    const float* xc = (const float*)d_in[0];
    const float* yc = (const float*)d_in[1];
    const float* xt = (const float*)d_in[2];
    const float* W0 = (const float*)d_in[3];
    const float* b0 = (const float*)d_in[4];
    const float* W1 = (const float*)d_in[5];
    const float* b1 = (const float*)d_in[6];
    const float* W2 = (const float*)d_in[7];
    const float* b2 = (const float*)d_in[8];
    const float* W3 = (const float*)d_in[9];
    const float* b3 = (const float*)d_in[10];
    float* out = (float*)d_out;

    // workspace (floats): sig[24576] pO[2.1M] pl[64K]  ~= 8.8 MB
    float* ws = (float*)d_ws;
    float* sig = ws;
    float* pO = sig + (size_t)BB * NTT * 3;
    float* pl = pO + (size_t)NTG * NCG * 2048;

    k_mlp<<<dim3(BB * NTT / 32), dim3(512), 0, stream>>>(xt, W0, b0, W1, b1, W2, b2,
                                                         W3, b3, sig);
    k_attn<<<dim3(NTG, NCG), dim3(256), 0, stream>>>(xc, yc, xt, sig, pO, pl);
    k_combine<<<dim3(NTG), dim3(256), 0, stream>>>(pO, pl, out);
}

// Round 6
// 143.960 us; speedup vs baseline: 1.0330x; 1.0330x over previous
//
#include <hip/hip_runtime.h>
#include <math.h>

#define BB 8
#define NCC 1024
#define NTT 1024
#define HH 128
#define DYY 32
#define HSTRIDE 129              /* hbuf stride: bank=(p+k)%32, conflict-free */

// ---------------- K1: fused MLP  sig = exp(mlp(xt))  ----------------
// 256 blocks x 512 threads; block = 32 points; thread = (jg=tid>>5, p=tid&31).
// W loads explicitly software-pipelined depth 8 (r5 post-mortem: compiler
// alone allocated 36 VGPR and serialized at L2 latency, VALUBusy 9%).
__global__ __launch_bounds__(512) void k_mlp(const float* __restrict__ xt,
                                             const float* __restrict__ W0,
                                             const float* __restrict__ b0,
                                             const float* __restrict__ W1,
                                             const float* __restrict__ b1,
                                             const float* __restrict__ W2,
                                             const float* __restrict__ b2,
                                             const float* __restrict__ W3,
                                             const float* __restrict__ b3,
                                             float* __restrict__ sig) {
    const int tid = threadIdx.x;
    const int jg = tid >> 5;        // 0..15 col-group (2 per wave)
    const int p = tid & 31;         // 0..31 point
    const int j0 = jg * 8;
    const int row0 = blockIdx.x * 32;

    __shared__ float hbuf[32 * HSTRIDE];   // 16.1 KB
    __shared__ float red[16 * 32 * 3];     // [jg][p][c]: bank=(3p+c)%32, conflict-free

    // ---- L0 ----
    const float* xr = xt + (size_t)(row0 + p) * 3;
    float x0 = xr[0], x1 = xr[1], x2 = xr[2];
    float o[8];
#pragma unroll
    for (int jj = 0; jj < 8; ++jj) {
        int j = j0 + jj;
        float a = b0[j];
        a = fmaf(x0, W0[0 * HH + j], a);
        a = fmaf(x1, W0[1 * HH + j], a);
        a = fmaf(x2, W0[2 * HH + j], a);
        o[jj] = fmaxf(a, 0.f);
    }
#pragma unroll
    for (int jj = 0; jj < 8; ++jj) hbuf[p * HSTRIDE + j0 + jj] = o[jj];
    __syncthreads();

    // ---- L1, L2: depth-8 pipelined ----
    for (int l = 0; l < 2; ++l) {
        const float* __restrict__ W = (l == 0) ? W1 : W2;
        const float* __restrict__ bi = (l == 0) ? b1 : b2;
        const float4* __restrict__ Wv = (const float4*)W;   // [k][32 float4]
        float acc[8];
#pragma unroll
        for (int jj = 0; jj < 8; ++jj) acc[jj] = bi[j0 + jj];

        float4 wa[8], wb[8];
        float hv[8];
#pragma unroll
        for (int i = 0; i < 8; ++i) {
            wa[i] = Wv[i * 32 + jg * 2];
            wb[i] = Wv[i * 32 + jg * 2 + 1];
            hv[i] = hbuf[p * HSTRIDE + i];
        }
        for (int k = 0; k < 120; k += 8) {      // chunks with always-valid prefetch
#pragma unroll
            for (int i = 0; i < 8; ++i) {
                float4 ca = wa[i], cb = wb[i];
                float ch = hv[i];
                int kn = k + 8 + i;
                wa[i] = Wv[kn * 32 + jg * 2];
                wb[i] = Wv[kn * 32 + jg * 2 + 1];
                hv[i] = hbuf[p * HSTRIDE + kn];
                acc[0] = fmaf(ch, ca.x, acc[0]);
                acc[1] = fmaf(ch, ca.y, acc[1]);
                acc[2] = fmaf(ch, ca.z, acc[2]);
                acc[3] = fmaf(ch, ca.w, acc[3]);
                acc[4] = fmaf(ch, cb.x, acc[4]);
                acc[5] = fmaf(ch, cb.y, acc[5]);
                acc[6] = fmaf(ch, cb.z, acc[6]);
                acc[7] = fmaf(ch, cb.w, acc[7]);
            }
        }
#pragma unroll
        for (int i = 0; i < 8; ++i) {           // peeled last chunk, no prefetch
            float4 ca = wa[i], cb = wb[i];
            float ch = hv[i];
            acc[0] = fmaf(ch, ca.x, acc[0]);
            acc[1] = fmaf(ch, ca.y, acc[1]);
            acc[2] = fmaf(ch, ca.z, acc[2]);
            acc[3] = fmaf(ch, ca.w, acc[3]);
            acc[4] = fmaf(ch, cb.x, acc[4]);
            acc[5] = fmaf(ch, cb.y, acc[5]);
            acc[6] = fmaf(ch, cb.z, acc[6]);
            acc[7] = fmaf(ch, cb.w, acc[7]);
        }
        __syncthreads();                         // hbuf reads complete
#pragma unroll
        for (int jj = 0; jj < 8; ++jj) o[jj] = fmaxf(acc[jj], 0.f);
        if (l == 0) {
#pragma unroll
            for (int jj = 0; jj < 8; ++jj) hbuf[p * HSTRIDE + j0 + jj] = o[jj];
            __syncthreads();
        }
    }

    // ---- L3 + exp ----
    float p0 = 0.f, p1 = 0.f, p2 = 0.f;
#pragma unroll
    for (int jj = 0; jj < 8; ++jj) {
        int j = j0 + jj;
        p0 = fmaf(o[jj], W3[j * 3 + 0], p0);
        p1 = fmaf(o[jj], W3[j * 3 + 1], p1);
        p2 = fmaf(o[jj], W3[j * 3 + 2], p2);
    }
    red[(jg * 32 + p) * 3 + 0] = p0;             // bank=(3p+c)%32: conflict-free
    red[(jg * 32 + p) * 3 + 1] = p1;
    red[(jg * 32 + p) * 3 + 2] = p2;
    __syncthreads();
    if (tid < 96) {
        int r = tid / 3, c = tid - r * 3;
        float v = b3[c];
#pragma unroll
        for (int g = 0; g < 16; ++g) v += red[(g * 32 + r) * 3 + c];
        sig[(size_t)(row0 + r) * 3 + c] = __expf(v);
    }
}

// ---------------- K2: fused attention (partials + combine + normalize) ----------------
// 256 blocks x 512 threads. Block = 32 targets (one batch); wave w = n-chunk
// [w*128, w*128+128). Lane = (tl=lane&31 target, dg=lane>>5 d-half), acc[16].
// yc: 4 lane-varying float4 loads per n (128 B unique/wave). e computed per
// lane (2x redundant). P<=0 (sig>0) => exp(P)<=1, no max subtraction; chunk
// partials merged in LDS, normalized, written directly — no pO/combine pass.
__global__ __launch_bounds__(512) void k_attn(const float* __restrict__ xc,
                                              const float* __restrict__ yc,
                                              const float* __restrict__ xt,
                                              const float* __restrict__ sig,
                                              float* __restrict__ out) {
    const int tid = threadIdx.x;
    const int w = tid >> 6;          // 0..7 n-chunk
    const int lane = tid & 63;
    const int tl = lane & 31;        // target within block
    const int dg = lane >> 5;        // 0..1 d-half
    const int t0 = blockIdx.x * 32;  // global target base
    const int b = blockIdx.x >> 5;   // batch

    const size_t t = (size_t)t0 + tl;
    float s0 = sig[t * 3 + 0], s1 = sig[t * 3 + 1], s2 = sig[t * 3 + 2];
    float a0 = xt[t * 3 + 0], a1 = xt[t * 3 + 1], a2 = xt[t * 3 + 2];

    float acc[16];
#pragma unroll
    for (int i = 0; i < 16; ++i) acc[i] = 0.f;
    float l = 0.f;

    const float* __restrict__ xcb = xc + ((size_t)b * NCC + w * 128) * 3;
    const float* __restrict__ ycb = yc + ((size_t)b * NCC + w * 128) * DYY + dg * 16;

    for (int nn = 0; nn < 128; nn += 4) {
        float4 q[4][4];
#pragma unroll
        for (int u = 0; u < 4; ++u) {
            const float* ycn = ycb + (size_t)(nn + u) * DYY;
            q[u][0] = *(const float4*)(ycn + 0);
            q[u][1] = *(const float4*)(ycn + 4);
            q[u][2] = *(const float4*)(ycn + 8);
            q[u][3] = *(const float4*)(ycn + 12);
        }
        float ee[4];
#pragma unroll
        for (int u = 0; u < 4; ++u) {
            const float* xcn = xcb + (nn + u) * 3;
            float d0 = xcn[0] - a0, d1 = xcn[1] - a1, d2 = xcn[2] - a2;
            float pp = fmaf(s0, d0 * d0, fmaf(s1, d1 * d1, s2 * (d2 * d2)));
            ee[u] = __expf(-pp);
            l += ee[u];
        }
#pragma unroll
        for (int u = 0; u < 4; ++u) {
            float e = ee[u];
            acc[0]  = fmaf(e, q[u][0].x, acc[0]);
            acc[1]  = fmaf(e, q[u][0].y, acc[1]);
            acc[2]  = fmaf(e, q[u][0].z, acc[2]);
            acc[3]  = fmaf(e, q[u][0].w, acc[3]);
            acc[4]  = fmaf(e, q[u][1].x, acc[4]);
            acc[5]  = fmaf(e, q[u][1].y, acc[5]);
            acc[6]  = fmaf(e, q[u][1].z, acc[6]);
            acc[7]  = fmaf(e, q[u][1].w, acc[7]);
            acc[8]  = fmaf(e, q[u][2].x, acc[8]);
            acc[9]  = fmaf(e, q[u][2].y, acc[9]);
            acc[10] = fmaf(e, q[u][2].z, acc[10]);
            acc[11] = fmaf(e, q[u][2].w, acc[11]);
            acc[12] = fmaf(e, q[u][3].x, acc[12]);
            acc[13] = fmaf(e, q[u][3].y, acc[13]);
            acc[14] = fmaf(e, q[u][3].z, acc[14]);
            acc[15] = fmaf(e, q[u][3].w, acc[15]);
        }
    }

    // ---- combine the 8 n-chunks in LDS, normalize, write ----
    __shared__ float sacc[8 * 32 * 33];   // [w][tl][d], stride 33: <=2-way (free)
    __shared__ float sl[8 * 32];
#pragma unroll
    for (int i = 0; i < 16; ++i)
        sacc[(w * 32 + tl) * 33 + dg * 16 + i] = acc[i];
    if (dg == 0) sl[w * 32 + tl] = l;
    __syncthreads();

#pragma unroll
    for (int idx = 0; idx < 1024; idx += 512) {
        int ii = idx + tid;
        int rtl = ii >> 5, d = ii & 31;
        float s = 0.f, lsum = 0.f;
#pragma unroll
        for (int ww = 0; ww < 8; ++ww) {
            s += sacc[(ww * 32 + rtl) * 33 + d];
            lsum += sl[ww * 32 + rtl];
        }
        out[(size_t)t0 * DYY + ii] = s / lsum;   // coalesced: out[(t0+rtl)*32 + d]
    }
}

extern "C" void kernel_launch(void* const* d_in, const int* in_sizes, int n_in,
                              void* d_out, int out_size, void* d_ws, size_t ws_size,
                              hipStream_t stream) {
    const float* xc = (const float*)d_in[0];
    const float* yc = (const float*)d_in[1];
    const float* xt = (const float*)d_in[2];
    const float* W0 = (const float*)d_in[3];
    const float* b0 = (const float*)d_in[4];
    const float* W1 = (const float*)d_in[5];
    const float* b1 = (const float*)d_in[6];
    const float* W2 = (const float*)d_in[7];
    const float* b2 = (const float*)d_in[8];
    const float* W3 = (const float*)d_in[9];
    const float* b3 = (const float*)d_in[10];
    float* out = (float*)d_out;

    float* sig = (float*)d_ws;   // 8192*3 floats = 96 KB

    k_mlp<<<dim3(BB * NTT / 32), dim3(512), 0, stream>>>(xt, W0, b0, W1, b1, W2, b2,
                                                         W3, b3, sig);
    k_attn<<<dim3(BB * NTT / 32), dim3(512), 0, stream>>>(xc, yc, xt, sig, out);
}

// Round 8
// 122.695 us; speedup vs baseline: 1.2121x; 1.1733x over previous
//
#include <hip/hip_runtime.h>
#include <math.h>

#define BB 8
#define NCC 1024
#define NTT 1024
#define HH 128
#define DYY 32
#define HSTRIDE 129              /* hbuf stride: bank=(p+k)%32, conflict-free */

// ---------------- K1: fused MLP  sig = exp(mlp(xt))  ----------------
// 256 blocks x 512 threads; block = 32 points; thread = (jg=tid>>5, p=tid&31).
// W loads explicitly software-pipelined depth 8 (r5: compiler alone allocated
// 36 VGPR and serialized at L2 latency).
__global__ __launch_bounds__(512) void k_mlp(const float* __restrict__ xt,
                                             const float* __restrict__ W0,
                                             const float* __restrict__ b0,
                                             const float* __restrict__ W1,
                                             const float* __restrict__ b1,
                                             const float* __restrict__ W2,
                                             const float* __restrict__ b2,
                                             const float* __restrict__ W3,
                                             const float* __restrict__ b3,
                                             float* __restrict__ sig) {
    const int tid = threadIdx.x;
    const int jg = tid >> 5;        // 0..15 col-group (2 per wave)
    const int p = tid & 31;         // 0..31 point
    const int j0 = jg * 8;
    const int row0 = blockIdx.x * 32;

    __shared__ float hbuf[32 * HSTRIDE];   // 16.1 KB
    __shared__ float red[16 * 32 * 3];     // [jg][p][c]: bank=(3p+c)%32, conflict-free

    // ---- L0 ----
    const float* xr = xt + (size_t)(row0 + p) * 3;
    float x0 = xr[0], x1 = xr[1], x2 = xr[2];
    float o[8];
#pragma unroll
    for (int jj = 0; jj < 8; ++jj) {
        int j = j0 + jj;
        float a = b0[j];
        a = fmaf(x0, W0[0 * HH + j], a);
        a = fmaf(x1, W0[1 * HH + j], a);
        a = fmaf(x2, W0[2 * HH + j], a);
        o[jj] = fmaxf(a, 0.f);
    }
#pragma unroll
    for (int jj = 0; jj < 8; ++jj) hbuf[p * HSTRIDE + j0 + jj] = o[jj];
    __syncthreads();

    // ---- L1, L2: depth-8 pipelined ----
    for (int l = 0; l < 2; ++l) {
        const float* __restrict__ W = (l == 0) ? W1 : W2;
        const float* __restrict__ bi = (l == 0) ? b1 : b2;
        const float4* __restrict__ Wv = (const float4*)W;   // [k][32 float4]
        float acc[8];
#pragma unroll
        for (int jj = 0; jj < 8; ++jj) acc[jj] = bi[j0 + jj];

        float4 wa[8], wb[8];
        float hv[8];
#pragma unroll
        for (int i = 0; i < 8; ++i) {
            wa[i] = Wv[i * 32 + jg * 2];
            wb[i] = Wv[i * 32 + jg * 2 + 1];
            hv[i] = hbuf[p * HSTRIDE + i];
        }
        for (int k = 0; k < 120; k += 8) {
#pragma unroll
            for (int i = 0; i < 8; ++i) {
                float4 ca = wa[i], cb = wb[i];
                float ch = hv[i];
                int kn = k + 8 + i;
                wa[i] = Wv[kn * 32 + jg * 2];
                wb[i] = Wv[kn * 32 + jg * 2 + 1];
                hv[i] = hbuf[p * HSTRIDE + kn];
                acc[0] = fmaf(ch, ca.x, acc[0]);
                acc[1] = fmaf(ch, ca.y, acc[1]);
                acc[2] = fmaf(ch, ca.z, acc[2]);
                acc[3] = fmaf(ch, ca.w, acc[3]);
                acc[4] = fmaf(ch, cb.x, acc[4]);
                acc[5] = fmaf(ch, cb.y, acc[5]);
                acc[6] = fmaf(ch, cb.z, acc[6]);
                acc[7] = fmaf(ch, cb.w, acc[7]);
            }
        }
#pragma unroll
        for (int i = 0; i < 8; ++i) {
            float4 ca = wa[i], cb = wb[i];
            float ch = hv[i];
            acc[0] = fmaf(ch, ca.x, acc[0]);
            acc[1] = fmaf(ch, ca.y, acc[1]);
            acc[2] = fmaf(ch, ca.z, acc[2]);
            acc[3] = fmaf(ch, ca.w, acc[3]);
            acc[4] = fmaf(ch, cb.x, acc[4]);
            acc[5] = fmaf(ch, cb.y, acc[5]);
            acc[6] = fmaf(ch, cb.z, acc[6]);
            acc[7] = fmaf(ch, cb.w, acc[7]);
        }
        __syncthreads();
#pragma unroll
        for (int jj = 0; jj < 8; ++jj) o[jj] = fmaxf(acc[jj], 0.f);
        if (l == 0) {
#pragma unroll
            for (int jj = 0; jj < 8; ++jj) hbuf[p * HSTRIDE + j0 + jj] = o[jj];
            __syncthreads();
        }
    }

    // ---- L3 + exp ----
    float p0 = 0.f, p1 = 0.f, p2 = 0.f;
#pragma unroll
    for (int jj = 0; jj < 8; ++jj) {
        int j = j0 + jj;
        p0 = fmaf(o[jj], W3[j * 3 + 0], p0);
        p1 = fmaf(o[jj], W3[j * 3 + 1], p1);
        p2 = fmaf(o[jj], W3[j * 3 + 2], p2);
    }
    red[(jg * 32 + p) * 3 + 0] = p0;
    red[(jg * 32 + p) * 3 + 1] = p1;
    red[(jg * 32 + p) * 3 + 2] = p2;
    __syncthreads();
    if (tid < 96) {
        int r = tid / 3, c = tid - r * 3;
        float v = b3[c];
#pragma unroll
        for (int g = 0; g < 16; ++g) v += red[(g * 32 + r) * 3 + c];
        sig[(size_t)(row0 + r) * 3 + c] = __expf(v);
    }
}

// ---------------- K2: fused attention, LDS-staged double-buffered ----------------
// 256 blocks x 512 threads; block = 32 targets of one batch. Loop over 8
// n-tiles of 128: yc tile (16 KB) + xc tile (1.5 KB) staged into LDS with
// per-lane coalesced float4 global loads (lane-VARYING addresses — r6 lesson:
// wave-uniform global addresses get scalarized and serialize on lgkmcnt).
// Inner loop: lane=(tl,dg) reads yc/xc from LDS (2 unique addrs/wave ->
// broadcast, free). Wave w covers n sub-range [w*16,w*16+16) of each tile.
// P<=0 (sig>0) => exp(P)<=1: no max subtraction, partials sum; combine in
// LDS (aliased over staging buffers), normalize, write directly.
// NOTE r7: no arrays of pointers into __shared__ (addrspacecast static-init
// compile error) — use computed offsets from one smem base instead.
__global__ __launch_bounds__(512) void k_attn(const float* __restrict__ xc,
                                              const float* __restrict__ yc,
                                              const float* __restrict__ xt,
                                              const float* __restrict__ sig,
                                              float* __restrict__ out) {
    const int tid = threadIdx.x;
    const int w = tid >> 6;          // 0..7
    const int lane = tid & 63;
    const int tl = lane & 31;        // target within block
    const int dg = lane >> 5;        // 0..1 d-half
    const int t0 = blockIdx.x * 32;
    const int b = blockIdx.x >> 5;

    // smem: yc0[4096] | yc1[4096] | xc0[384] | xc1[384]  = 8960 floats (35 KB)
    __shared__ float smem[8960];

    const size_t t = (size_t)t0 + tl;
    const float s0 = sig[t * 3 + 0], s1 = sig[t * 3 + 1], s2 = sig[t * 3 + 2];
    const float a0 = xt[t * 3 + 0], a1 = xt[t * 3 + 1], a2 = xt[t * 3 + 2];

    const float4* __restrict__ ycG = (const float4*)(yc + (size_t)b * NCC * DYY);
    const float4* __restrict__ xcG = (const float4*)(xc + (size_t)b * NCC * 3);

    float acc[16];
#pragma unroll
    for (int i = 0; i < 16; ++i) acc[i] = 0.f;
    float l = 0.f;

    // ---- prologue: stage tile 0 ----
    {
        float4 y0 = ycG[tid], y1 = ycG[512 + tid];
        ((float4*)smem)[tid] = y0;
        ((float4*)smem)[512 + tid] = y1;
        if (tid < 96) ((float4*)(smem + 8192))[tid] = xcG[tid];
    }
    __syncthreads();

    for (int tile = 0; tile < 8; ++tile) {
        const int cur = tile & 1;
        float4 y0n, y1n, xn;
        if (tile < 7) {                       // issue next-tile loads (overlap compute)
            y0n = ycG[(tile + 1) * 1024 + tid];
            y1n = ycG[(tile + 1) * 1024 + 512 + tid];
            if (tid < 96) xn = xcG[(tile + 1) * 96 + tid];
        }

        // ---- compute on current tile: my 16 n's ----
        const float* yb = smem + cur * 4096;
        const float* xb = smem + 8192 + cur * 384;
#pragma unroll 4
        for (int i = 0; i < 16; ++i) {
            const int nn = w * 16 + i;
            float d0 = xb[nn * 3 + 0] - a0;
            float d1 = xb[nn * 3 + 1] - a1;
            float d2 = xb[nn * 3 + 2] - a2;
            float pp = fmaf(s0, d0 * d0, fmaf(s1, d1 * d1, s2 * (d2 * d2)));
            float e = __expf(-pp);
            l += e;
            const float4* yv = (const float4*)(yb + nn * DYY + dg * 16);
            float4 q0 = yv[0], q1 = yv[1], q2 = yv[2], q3 = yv[3];
            acc[0]  = fmaf(e, q0.x, acc[0]);
            acc[1]  = fmaf(e, q0.y, acc[1]);
            acc[2]  = fmaf(e, q0.z, acc[2]);
            acc[3]  = fmaf(e, q0.w, acc[3]);
            acc[4]  = fmaf(e, q1.x, acc[4]);
            acc[5]  = fmaf(e, q1.y, acc[5]);
            acc[6]  = fmaf(e, q1.z, acc[6]);
            acc[7]  = fmaf(e, q1.w, acc[7]);
            acc[8]  = fmaf(e, q2.x, acc[8]);
            acc[9]  = fmaf(e, q2.y, acc[9]);
            acc[10] = fmaf(e, q2.z, acc[10]);
            acc[11] = fmaf(e, q2.w, acc[11]);
            acc[12] = fmaf(e, q3.x, acc[12]);
            acc[13] = fmaf(e, q3.y, acc[13]);
            acc[14] = fmaf(e, q3.z, acc[14]);
            acc[15] = fmaf(e, q3.w, acc[15]);
        }
        __syncthreads();                      // tile reads done
        if (tile < 7) {
            const int nxt = 1 - cur;
            ((float4*)(smem + nxt * 4096))[tid] = y0n;
            ((float4*)(smem + nxt * 4096))[512 + tid] = y1n;
            if (tid < 96) ((float4*)(smem + 8192 + nxt * 384))[tid] = xn;
            __syncthreads();                  // staging visible
        }
    }

    // ---- combine 8 waves in LDS (aliases staging), normalize, write ----
    // sacc: [w][tl] stride 33 (8448 floats), sl at 8448..8704
#pragma unroll
    for (int i = 0; i < 16; ++i)
        smem[(w * 32 + tl) * 33 + dg * 16 + i] = acc[i];
    if (dg == 0) smem[8448 + w * 32 + tl] = l;
    __syncthreads();

#pragma unroll
    for (int idx = 0; idx < 1024; idx += 512) {
        int ii = idx + tid;
        int rtl = ii >> 5, d = ii & 31;
        float s = 0.f, lsum = 0.f;
#pragma unroll
        for (int ww = 0; ww < 8; ++ww) {
            s += smem[(ww * 32 + rtl) * 33 + d];
            lsum += smem[8448 + ww * 32 + rtl];
        }
        out[(size_t)t0 * DYY + ii] = s / lsum;
    }
}

extern "C" void kernel_launch(void* const* d_in, const int* in_sizes, int n_in,
                              void* d_out, int out_size, void* d_ws, size_t ws_size,
                              hipStream_t stream) {
    const float* xc = (const float*)d_in[0];
    const float* yc = (const float*)d_in[1];
    const float* xt = (const float*)d_in[2];
    const float* W0 = (const float*)d_in[3];
    const float* b0 = (const float*)d_in[4];
    const float* W1 = (const float*)d_in[5];
    const float* b1 = (const float*)d_in[6];
    const float* W2 = (const float*)d_in[7];
    const float* b2 = (const float*)d_in[8];
    const float* W3 = (const float*)d_in[9];
    const float* b3 = (const float*)d_in[10];
    float* out = (float*)d_out;

    float* sig = (float*)d_ws;   // 8192*3 floats = 96 KB

    k_mlp<<<dim3(BB * NTT / 32), dim3(512), 0, stream>>>(xt, W0, b0, W1, b1, W2, b2,
                                                         W3, b3, sig);
    k_attn<<<dim3(BB * NTT / 32), dim3(512), 0, stream>>>(xc, yc, xt, sig, out);
}

// Round 9
// 122.680 us; speedup vs baseline: 1.2122x; 1.0001x over previous
//
#include <hip/hip_runtime.h>
#include <math.h>

#define BB 8
#define NCC 1024
#define NTT 1024
#define HH 128
#define DYY 32
#define LOG2E 1.44269504088896340736f

// LDS arena layout (floats):
//   yc0   [    0,  4096)   attn yc tile buffer 0 (16 KB)
//   yc1   [ 4096,  8192)   attn yc tile buffer 1
//   xc0   [ 8192,  8576)   attn xc tile buffer 0
//   xc1   [ 8576,  8960)   attn xc tile buffer 1
//   sigl  [ 8960,  9056)   sig*log2e for the block's 32 targets
//   hbuf  [ 9056, 13184)   MLP activations 32x129 (stride 129: conflict-free)
//   red   [13184, 14720)   MLP L3 reduction scratch
// epilogue aliases [0, 8704) as sacc/sl after the last tile barrier.
#define YC0 0
#define XC0 8192
#define SIGL 8960
#define HB 9056
#define RED 13184
#define HSTRIDE 129

// ---------------- fused kernel: sig = exp(mlp(xt)); out = softmax-attn ----------------
// 256 blocks x 512 threads; block = 32 targets of one batch.
// Phase 1 (MLP): thread = (jg=tid>>5 col-group, p=tid&31 point); W loads
// software-pipelined depth 8 (r5 lesson: compiler alone serializes at L2 lat).
// Phase 2 (attn): thread = (w=tid>>6 n-chunk, tl target, dg d-half); yc/xc
// staged in LDS via lane-varying float4 loads (r6 lesson: wave-uniform global
// addresses get scalarized), prefetch distance 2. P<=0 => exp(P)<=1, no max
// subtraction needed; partials merge in LDS; normalized output written direct.
// r7 lesson: no arrays of pointers into __shared__ (addrspacecast error).
__global__ __launch_bounds__(512) void k_fused(const float* __restrict__ xc,
                                               const float* __restrict__ yc,
                                               const float* __restrict__ xt,
                                               const float* __restrict__ W0,
                                               const float* __restrict__ b0,
                                               const float* __restrict__ W1,
                                               const float* __restrict__ b1,
                                               const float* __restrict__ W2,
                                               const float* __restrict__ b2,
                                               const float* __restrict__ W3,
                                               const float* __restrict__ b3,
                                               float* __restrict__ out) {
    const int tid = threadIdx.x;
    const int t0 = blockIdx.x * 32;      // target base (== row0)
    const int b = blockIdx.x >> 5;       // batch

    __shared__ float smem[14720];        // 57.5 KB

    const float4* __restrict__ ycG = (const float4*)(yc + (size_t)b * NCC * DYY);
    const float4* __restrict__ xcG = (const float4*)(xc + (size_t)b * NCC * 3);

    // ---- issue attn tile-0/1 staging loads NOW (land during MLP compute) ----
    float4 y00 = ycG[tid], y01 = ycG[512 + tid];
    float4 y10 = ycG[1024 + tid], y11 = ycG[1536 + tid];
    float4 xp0, xp1;
    if (tid < 96) { xp0 = xcG[tid]; xp1 = xcG[96 + tid]; }

    // ================= phase 1: MLP =================
    {
        const int jg = tid >> 5;         // 0..15 col-group (2 per wave)
        const int p = tid & 31;          // 0..31 point
        const int j0 = jg * 8;

        // ---- L0 ----
        const float* xr = xt + (size_t)(t0 + p) * 3;
        float x0 = xr[0], x1 = xr[1], x2 = xr[2];
        float o[8];
#pragma unroll
        for (int jj = 0; jj < 8; ++jj) {
            int j = j0 + jj;
            float a = b0[j];
            a = fmaf(x0, W0[0 * HH + j], a);
            a = fmaf(x1, W0[1 * HH + j], a);
            a = fmaf(x2, W0[2 * HH + j], a);
            o[jj] = fmaxf(a, 0.f);
        }
#pragma unroll
        for (int jj = 0; jj < 8; ++jj) smem[HB + p * HSTRIDE + j0 + jj] = o[jj];

        // ---- park attn tiles 0/1 in LDS (frees the prefetch VGPRs) ----
        ((float4*)(smem + YC0))[tid] = y00;
        ((float4*)(smem + YC0))[512 + tid] = y01;
        ((float4*)(smem + YC0 + 4096))[tid] = y10;
        ((float4*)(smem + YC0 + 4096))[512 + tid] = y11;
        if (tid < 96) {
            ((float4*)(smem + XC0))[tid] = xp0;
            ((float4*)(smem + XC0 + 384))[tid] = xp1;
        }
        __syncthreads();

        // ---- L1, L2: depth-8 pipelined W stream ----
        for (int l = 0; l < 2; ++l) {
            const float* __restrict__ W = (l == 0) ? W1 : W2;
            const float* __restrict__ bi = (l == 0) ? b1 : b2;
            const float4* __restrict__ Wv = (const float4*)W;   // [k][32 float4]
            float acc[8];
#pragma unroll
            for (int jj = 0; jj < 8; ++jj) acc[jj] = bi[j0 + jj];

            float4 wa[8], wb[8];
            float hv[8];
#pragma unroll
            for (int i = 0; i < 8; ++i) {
                wa[i] = Wv[i * 32 + jg * 2];
                wb[i] = Wv[i * 32 + jg * 2 + 1];
                hv[i] = smem[HB + p * HSTRIDE + i];
            }
            for (int k = 0; k < 120; k += 8) {
#pragma unroll
                for (int i = 0; i < 8; ++i) {
                    float4 ca = wa[i], cb = wb[i];
                    float ch = hv[i];
                    int kn = k + 8 + i;
                    wa[i] = Wv[kn * 32 + jg * 2];
                    wb[i] = Wv[kn * 32 + jg * 2 + 1];
                    hv[i] = smem[HB + p * HSTRIDE + kn];
                    acc[0] = fmaf(ch, ca.x, acc[0]);
                    acc[1] = fmaf(ch, ca.y, acc[1]);
                    acc[2] = fmaf(ch, ca.z, acc[2]);
                    acc[3] = fmaf(ch, ca.w, acc[3]);
                    acc[4] = fmaf(ch, cb.x, acc[4]);
                    acc[5] = fmaf(ch, cb.y, acc[5]);
                    acc[6] = fmaf(ch, cb.z, acc[6]);
                    acc[7] = fmaf(ch, cb.w, acc[7]);
                }
            }
#pragma unroll
            for (int i = 0; i < 8; ++i) {
                float4 ca = wa[i], cb = wb[i];
                float ch = hv[i];
                acc[0] = fmaf(ch, ca.x, acc[0]);
                acc[1] = fmaf(ch, ca.y, acc[1]);
                acc[2] = fmaf(ch, ca.z, acc[2]);
                acc[3] = fmaf(ch, ca.w, acc[3]);
                acc[4] = fmaf(ch, cb.x, acc[4]);
                acc[5] = fmaf(ch, cb.y, acc[5]);
                acc[6] = fmaf(ch, cb.z, acc[6]);
                acc[7] = fmaf(ch, cb.w, acc[7]);
            }
            __syncthreads();
#pragma unroll
            for (int jj = 0; jj < 8; ++jj) o[jj] = fmaxf(acc[jj], 0.f);
            if (l == 0) {
#pragma unroll
                for (int jj = 0; jj < 8; ++jj) smem[HB + p * HSTRIDE + j0 + jj] = o[jj];
                __syncthreads();
            }
        }

        // ---- L3 + exp -> sig*log2e into LDS ----
        float p0 = 0.f, p1 = 0.f, p2 = 0.f;
#pragma unroll
        for (int jj = 0; jj < 8; ++jj) {
            int j = j0 + jj;
            p0 = fmaf(o[jj], W3[j * 3 + 0], p0);
            p1 = fmaf(o[jj], W3[j * 3 + 1], p1);
            p2 = fmaf(o[jj], W3[j * 3 + 2], p2);
        }
        smem[RED + (jg * 32 + p) * 3 + 0] = p0;   // bank=(3p+c)%32: conflict-free
        smem[RED + (jg * 32 + p) * 3 + 1] = p1;
        smem[RED + (jg * 32 + p) * 3 + 2] = p2;
        __syncthreads();
        if (tid < 96) {
            int r = tid / 3, c = tid - r * 3;
            float v = b3[c];
#pragma unroll
            for (int g = 0; g < 16; ++g) v += smem[RED + (g * 32 + r) * 3 + c];
            smem[SIGL + r * 3 + c] = __expf(v) * LOG2E;
        }
        __syncthreads();
    }

    // ================= phase 2: attention =================
    const int w = tid >> 6;          // 0..7 n-chunk
    const int lane = tid & 63;
    const int tl = lane & 31;        // target within block
    const int dg = lane >> 5;        // 0..1 d-half

    const float s0 = smem[SIGL + tl * 3 + 0];
    const float s1 = smem[SIGL + tl * 3 + 1];
    const float s2 = smem[SIGL + tl * 3 + 2];
    const size_t t = (size_t)t0 + tl;
    const float a0 = xt[t * 3 + 0], a1 = xt[t * 3 + 1], a2 = xt[t * 3 + 2];

    float acc[16];
#pragma unroll
    for (int i = 0; i < 16; ++i) acc[i] = 0.f;
    float l = 0.f;

    for (int tile = 0; tile < 8; ++tile) {
        const int cur = tile & 1;
        float4 y0n, y1n, xn;
        if (tile < 6) {                       // prefetch tile+2 (distance 2)
            y0n = ycG[(tile + 2) * 1024 + tid];
            y1n = ycG[(tile + 2) * 1024 + 512 + tid];
            if (tid < 96) xn = xcG[(tile + 2) * 96 + tid];
        }

        const float* yb = smem + YC0 + cur * 4096;
        const float* xb = smem + XC0 + cur * 384;
#pragma unroll 4
        for (int i = 0; i < 16; ++i) {
            const int nn = w * 16 + i;
            float d0 = xb[nn * 3 + 0] - a0;
            float d1 = xb[nn * 3 + 1] - a1;
            float d2 = xb[nn * 3 + 2] - a2;
            float pp = fmaf(s0, d0 * d0, fmaf(s1, d1 * d1, s2 * (d2 * d2)));
            float e = exp2f(-pp);
            l += e;
            const float4* yv = (const float4*)(yb + nn * DYY + dg * 16);
            float4 q0 = yv[0], q1 = yv[1], q2 = yv[2], q3 = yv[3];
            acc[0]  = fmaf(e, q0.x, acc[0]);
            acc[1]  = fmaf(e, q0.y, acc[1]);
            acc[2]  = fmaf(e, q0.z, acc[2]);
            acc[3]  = fmaf(e, q0.w, acc[3]);
            acc[4]  = fmaf(e, q1.x, acc[4]);
            acc[5]  = fmaf(e, q1.y, acc[5]);
            acc[6]  = fmaf(e, q1.z, acc[6]);
            acc[7]  = fmaf(e, q1.w, acc[7]);
            acc[8]  = fmaf(e, q2.x, acc[8]);
            acc[9]  = fmaf(e, q2.y, acc[9]);
            acc[10] = fmaf(e, q2.z, acc[10]);
            acc[11] = fmaf(e, q2.w, acc[11]);
            acc[12] = fmaf(e, q3.x, acc[12]);
            acc[13] = fmaf(e, q3.y, acc[13]);
            acc[14] = fmaf(e, q3.z, acc[14]);
            acc[15] = fmaf(e, q3.w, acc[15]);
        }
        __syncthreads();                      // tile reads done
        if (tile < 6) {                       // write tile+2 into freed buffer
            ((float4*)(smem + YC0 + cur * 4096))[tid] = y0n;
            ((float4*)(smem + YC0 + cur * 4096))[512 + tid] = y1n;
            if (tid < 96) ((float4*)(smem + XC0 + cur * 384))[tid] = xn;
            __syncthreads();
        }
    }

    // ---- combine 8 waves in LDS (aliases tile buffers), normalize, write ----
#pragma unroll
    for (int i = 0; i < 16; ++i)
        smem[(w * 32 + tl) * 33 + dg * 16 + i] = acc[i];
    if (dg == 0) smem[8448 + w * 32 + tl] = l;
    __syncthreads();

#pragma unroll
    for (int idx = 0; idx < 1024; idx += 512) {
        int ii = idx + tid;
        int rtl = ii >> 5, d = ii & 31;
        float s = 0.f, lsum = 0.f;
#pragma unroll
        for (int ww = 0; ww < 8; ++ww) {
            s += smem[(ww * 32 + rtl) * 33 + d];
            lsum += smem[8448 + ww * 32 + rtl];
        }
        out[(size_t)t0 * DYY + ii] = s / lsum;
    }
}

extern "C" void kernel_launch(void* const* d_in, const int* in_sizes, int n_in,
                              void* d_out, int out_size, void* d_ws, size_t ws_size,
                              hipStream_t stream) {
    const float* xc = (const float*)d_in[0];
    const float* yc = (const float*)d_in[1];
    const float* xt = (const float*)d_in[2];
    const float* W0 = (const float*)d_in[3];
    const float* b0 = (const float*)d_in[4];
    const float* W1 = (const float*)d_in[5];
    const float* b1 = (const float*)d_in[6];
    const float* W2 = (const float*)d_in[7];
    const float* b2 = (const float*)d_in[8];
    const float* W3 = (const float*)d_in[9];
    const float* b3 = (const float*)d_in[10];
    float* out = (float*)d_out;

    k_fused<<<dim3(BB * NTT / 32), dim3(512), 0, stream>>>(xc, yc, xt, W0, b0, W1, b1,
                                                           W2, b2, W3, b3, out);
}